// Round 4
// baseline (16015.840 us; speedup 1.0000x reference)
//
#include <hip/hip_runtime.h>

#define D 128
#define KN 17
#define NEIGH 16
#define SINKI 20
#define TINYF 1e-30f

__device__ __forceinline__ float4 fma4(float a, const float4 b, const float4 c) {
  return make_float4(fmaf(a, b.x, c.x), fmaf(a, b.y, c.y),
                     fmaf(a, b.z, c.z), fmaf(a, b.w, c.w));
}

// block = 256 threads = 4 node-slots of one wave each.
// LDS: K (64KB) + K^T (64KB) + 4 half-buffers (17x64 f32 each) = 145 KB.
__global__ __launch_bounds__(256, 1)
void wgcn_hop(const float* __restrict__ Xin,
              const float* __restrict__ Cmat,
              const int* __restrict__ neigh,
              float* __restrict__ Xout,
              int n_nodes) {
  __shared__ float Kls[D][D];    // K[e][d] = exp(-C[e][d]/eps)
  __shared__ float KTls[D][D];   // KT[e][d] = K[d][e]
  __shared__ float ubuf[4][KN][64];

  const int tid = threadIdx.x;

  // Stage Gibbs kernel and its transpose (once per block).
  for (int base = tid * 4; base < D * D; base += 1024) {
    const int r = base >> 7;
    const int c0 = base & 127;
    float4 cv = *reinterpret_cast<const float4*>(&Cmat[base]);
    float4 kv;
    kv.x = expf(-cv.x / 0.1f);
    kv.y = expf(-cv.y / 0.1f);
    kv.z = expf(-cv.z / 0.1f);
    kv.w = expf(-cv.w / 0.1f);
    *reinterpret_cast<float4*>(&Kls[r][c0]) = kv;
    KTls[c0 + 0][r] = kv.x;
    KTls[c0 + 1][r] = kv.y;
    KTls[c0 + 2][r] = kv.z;
    KTls[c0 + 3][r] = kv.w;
  }
  __syncthreads();

  const int slot = tid >> 6;      // node slot (one wave)
  const int lane = tid & 63;
  const int g = lane >> 5;        // row-group: 0 -> rows 0..8, 1 -> rows 9..16
  const int m = lane & 31;        // column quad index
  const int d4 = m << 2;          // first owned column
  const int nrows = g ? (KN - 9) : 9;
  const int krow0 = g ? 9 : 0;
  float (*ub)[64] = ubuf[slot];

  const int slot_id = blockIdx.x * 4 + slot;
  const int slot_cnt = gridDim.x * 4;

  for (int n = slot_id; n < n_nodes; n += slot_cnt) {
    float4 mu4[9], w4[9], acc4[9];
    float4 bvec = make_float4(0.f, 0.f, 0.f, 0.f);

    // ---- gather neighbor distributions, row-normalize ----
#pragma unroll
    for (int i = 0; i < 9; ++i) {
      if (i < nrows) {
        const int k = krow0 + i;
        const int src = (k < NEIGH) ? neigh[n * NEIGH + k] : n;
        float4 x = *reinterpret_cast<const float4*>(&Xin[(long)src * D + d4]);
        float s = x.x + x.y + x.z + x.w;
        s += __shfl_xor(s, 16, 64);
        s += __shfl_xor(s, 8, 64);
        s += __shfl_xor(s, 4, 64);
        s += __shfl_xor(s, 2, 64);
        s += __shfl_xor(s, 1, 64);
        const float inv = __builtin_amdgcn_rcpf(s + TINYF);
        mu4[i] = make_float4(x.x * inv, x.y * inv, x.z * inv, x.w * inv);
        w4[i] = make_float4(1.f, 1.f, 1.f, 1.f);
      }
    }

    for (int it = 0; it < SINKI; ++it) {
      // ---------------- MM1: KTu[k][d] = sum_e u[k][e] * K[e][d] ----------------
#pragma unroll
      for (int i = 0; i < 9; ++i) acc4[i] = make_float4(0.f, 0.f, 0.f, 0.f);
      for (int h = 0; h < 2; ++h) {
        asm volatile("s_waitcnt lgkmcnt(0)" ::: "memory");
        if ((m >> 4) == h) {
#pragma unroll
          for (int i = 0; i < 9; ++i)
            if (i < nrows)
              *reinterpret_cast<float4*>(&ub[krow0 + i][d4 - (h << 6)]) = w4[i];
        }
        asm volatile("s_waitcnt lgkmcnt(0)" ::: "memory");
#pragma unroll 2
        for (int eq = 0; eq < 16; ++eq) {
          const int e0 = (h << 6) | (eq << 2);
          const float4 K0 = *reinterpret_cast<const float4*>(&Kls[e0 + 0][d4]);
          const float4 K1 = *reinterpret_cast<const float4*>(&Kls[e0 + 1][d4]);
          const float4 K2 = *reinterpret_cast<const float4*>(&Kls[e0 + 2][d4]);
          const float4 K3 = *reinterpret_cast<const float4*>(&Kls[e0 + 3][d4]);
          float4 uqv[9];
#pragma unroll
          for (int i = 0; i < 9; ++i)
            if (i < nrows)
              uqv[i] = *reinterpret_cast<const float4*>(&ub[krow0 + i][eq << 2]);
#pragma unroll
          for (int i = 0; i < 9; ++i)
            if (i < nrows) {
              float4 a = acc4[i];
              a = fma4(uqv[i].x, K0, a);
              a = fma4(uqv[i].y, K1, a);
              a = fma4(uqv[i].z, K2, a);
              a = fma4(uqv[i].w, K3, a);
              acc4[i] = a;
            }
        }
      }
      // v = mu / (KTu + TINY)
#pragma unroll
      for (int i = 0; i < 9; ++i)
        if (i < nrows) {
          w4[i].x = mu4[i].x * __builtin_amdgcn_rcpf(acc4[i].x + TINYF);
          w4[i].y = mu4[i].y * __builtin_amdgcn_rcpf(acc4[i].y + TINYF);
          w4[i].z = mu4[i].z * __builtin_amdgcn_rcpf(acc4[i].z + TINYF);
          w4[i].w = mu4[i].w * __builtin_amdgcn_rcpf(acc4[i].w + TINYF);
        }

      // ---------------- MM2: Kv[k][d] = sum_e v[k][e] * K[d][e] ----------------
#pragma unroll
      for (int i = 0; i < 9; ++i) acc4[i] = make_float4(0.f, 0.f, 0.f, 0.f);
      for (int h = 0; h < 2; ++h) {
        asm volatile("s_waitcnt lgkmcnt(0)" ::: "memory");
        if ((m >> 4) == h) {
#pragma unroll
          for (int i = 0; i < 9; ++i)
            if (i < nrows)
              *reinterpret_cast<float4*>(&ub[krow0 + i][d4 - (h << 6)]) = w4[i];
        }
        asm volatile("s_waitcnt lgkmcnt(0)" ::: "memory");
#pragma unroll 2
        for (int eq = 0; eq < 16; ++eq) {
          const int e0 = (h << 6) | (eq << 2);
          const float4 K0 = *reinterpret_cast<const float4*>(&KTls[e0 + 0][d4]);
          const float4 K1 = *reinterpret_cast<const float4*>(&KTls[e0 + 1][d4]);
          const float4 K2 = *reinterpret_cast<const float4*>(&KTls[e0 + 2][d4]);
          const float4 K3 = *reinterpret_cast<const float4*>(&KTls[e0 + 3][d4]);
          float4 uqv[9];
#pragma unroll
          for (int i = 0; i < 9; ++i)
            if (i < nrows)
              uqv[i] = *reinterpret_cast<const float4*>(&ub[krow0 + i][eq << 2]);
#pragma unroll
          for (int i = 0; i < 9; ++i)
            if (i < nrows) {
              float4 a = acc4[i];
              a = fma4(uqv[i].x, K0, a);
              a = fma4(uqv[i].y, K1, a);
              a = fma4(uqv[i].z, K2, a);
              a = fma4(uqv[i].w, K3, a);
              acc4[i] = a;
            }
        }
      }
      // b = exp2( (1/17) * sum_k log2(Kv + TINY) );  u = b / (Kv + TINY)
      float4 part = make_float4(0.f, 0.f, 0.f, 0.f);
#pragma unroll
      for (int i = 0; i < 9; ++i)
        if (i < nrows) {
          acc4[i].x += TINYF; acc4[i].y += TINYF;
          acc4[i].z += TINYF; acc4[i].w += TINYF;
          part.x += __builtin_amdgcn_logf(acc4[i].x);
          part.y += __builtin_amdgcn_logf(acc4[i].y);
          part.z += __builtin_amdgcn_logf(acc4[i].z);
          part.w += __builtin_amdgcn_logf(acc4[i].w);
        }
      part.x += __shfl_xor(part.x, 32, 64);
      part.y += __shfl_xor(part.y, 32, 64);
      part.z += __shfl_xor(part.z, 32, 64);
      part.w += __shfl_xor(part.w, 32, 64);
      const float w17 = 1.0f / 17.0f;
      bvec = make_float4(__builtin_amdgcn_exp2f(part.x * w17),
                         __builtin_amdgcn_exp2f(part.y * w17),
                         __builtin_amdgcn_exp2f(part.z * w17),
                         __builtin_amdgcn_exp2f(part.w * w17));
#pragma unroll
      for (int i = 0; i < 9; ++i)
        if (i < nrows) {
          w4[i].x = bvec.x * __builtin_amdgcn_rcpf(acc4[i].x);
          w4[i].y = bvec.y * __builtin_amdgcn_rcpf(acc4[i].y);
          w4[i].z = bvec.z * __builtin_amdgcn_rcpf(acc4[i].z);
          w4[i].w = bvec.w * __builtin_amdgcn_rcpf(acc4[i].w);
        }
    }

    if (g == 0)
      *reinterpret_cast<float4*>(&Xout[(long)n * D + d4]) = bvec;
  }
}

extern "C" void kernel_launch(void* const* d_in, const int* in_sizes, int n_in,
                              void* d_out, int out_size, void* d_ws, size_t ws_size,
                              hipStream_t stream) {
  const float* trans_X = (const float*)d_in[0];
  const float* cost = (const float*)d_in[1];
  const int* neigh = (const int*)d_in[2];
  float* out = (float*)d_out;
  float* X1 = (float*)d_ws;   // intermediate hop output, 20000*128 f32 = 10.24 MB
  const int n = in_sizes[0] / D;

  dim3 grid(256), block(256);
  hipLaunchKernelGGL(wgcn_hop, grid, block, 0, stream, trans_X, cost, neigh, X1, n);
  hipLaunchKernelGGL(wgcn_hop, grid, block, 0, stream, X1, cost, neigh, out, n);
}

// Round 5
// 15990.636 us; speedup vs baseline: 1.0016x; 1.0016x over previous
//
#include <hip/hip_runtime.h>

#define D 128
#define KN 17
#define NEIGH 16
#define SINKI 20
#define TINYF 1e-30f

__device__ __forceinline__ float4 fma4(float a, const float4 b, const float4 c) {
  return make_float4(fmaf(a, b.x, c.x), fmaf(a, b.y, c.y),
                     fmaf(a, b.z, c.z), fmaf(a, b.w, c.w));
}

// block = 512 threads = 8 node-slots of one wave each.
// LDS: swizzled K (64KB) + 8 slot-buffers (17x128 f32 = 8.5KB each) = 132 KB.
// K[e][d] stored at row e, quad (d>>2)^((e>>2)&31):
//   - MM1 (row access, lane-distinct quads)  -> conflict-free
//   - MM2 (dot access, rows 4m+c, quad eq^m) -> 32 distinct quads, 2-way g-alias = free
__global__ __launch_bounds__(512, 1)
void wgcn_hop(const float* __restrict__ Xin,
              const float* __restrict__ Cmat,
              const int* __restrict__ neigh,
              float* __restrict__ Xout,
              int n_nodes) {
  __shared__ float Kls[D][D];
  __shared__ float ubuf[8][KN][D];

  const int tid = threadIdx.x;

  // ---- stage swizzled Gibbs kernel (once per block) ----
  for (int base = tid * 4; base < D * D; base += 2048) {
    const int r = base >> 7;
    const int c0 = base & 127;
    float4 cv = *reinterpret_cast<const float4*>(&Cmat[base]);
    float4 kv;
    kv.x = expf(-cv.x / 0.1f);
    kv.y = expf(-cv.y / 0.1f);
    kv.z = expf(-cv.z / 0.1f);
    kv.w = expf(-cv.w / 0.1f);
    const int qp = (((c0 >> 2) ^ ((r >> 2) & 31)) << 2);
    *reinterpret_cast<float4*>(&Kls[r][qp]) = kv;
  }
  __syncthreads();

  const int slot = tid >> 6;      // node slot (one wave)
  const int lane = tid & 63;
  const int g = lane >> 5;        // half: rows 0..8 vs 9..16 (MM1), e-halves (MM2)
  const int m = lane & 31;        // column-quad index
  const int d4 = m << 2;
  const int nrows = g ? (KN - 9) : 9;
  const int krow0 = g ? 9 : 0;
  float (*U)[D] = ubuf[slot];

  const int slot_id = blockIdx.x * 8 + slot;
  const int slot_cnt = gridDim.x * 8;

  for (int n = slot_id; n < n_nodes; n += slot_cnt) {
    float4 mu4[9];
    float4 bvec = make_float4(0.f, 0.f, 0.f, 0.f);

    // ---- gather neighbor distributions, row-normalize; u0 = 1 ----
#pragma unroll
    for (int i = 0; i < 9; ++i) {
      if (i < nrows) {
        const int k = krow0 + i;
        const int src = (k < NEIGH) ? neigh[n * NEIGH + k] : n;
        float4 x = *reinterpret_cast<const float4*>(&Xin[(long)src * D + d4]);
        float s = x.x + x.y + x.z + x.w;
        s += __shfl_xor(s, 16, 64);
        s += __shfl_xor(s, 8, 64);
        s += __shfl_xor(s, 4, 64);
        s += __shfl_xor(s, 2, 64);
        s += __shfl_xor(s, 1, 64);
        const float inv = __builtin_amdgcn_rcpf(s + TINYF);
        mu4[i] = make_float4(x.x * inv, x.y * inv, x.z * inv, x.w * inv);
        *reinterpret_cast<float4*>(&U[k][d4]) = make_float4(1.f, 1.f, 1.f, 1.f);
      }
    }
    asm volatile("s_waitcnt lgkmcnt(0)" ::: "memory");

    for (int it = 0; it < SINKI; ++it) {
      // ---------- MM1: KTu[k][d] = sum_e u[k][e] * K[e][d]  (rows g-split) ----------
      float4 acc[9];
#pragma unroll
      for (int i = 0; i < 9; ++i) acc[i] = make_float4(0.f, 0.f, 0.f, 0.f);
#pragma unroll 2
      for (int eq = 0; eq < 32; ++eq) {
        const int e0 = eq << 2;
        const int qp = ((m ^ eq) << 2);
        const float4 K0 = *reinterpret_cast<const float4*>(&Kls[e0 + 0][qp]);
        const float4 K1 = *reinterpret_cast<const float4*>(&Kls[e0 + 1][qp]);
        const float4 K2 = *reinterpret_cast<const float4*>(&Kls[e0 + 2][qp]);
        const float4 K3 = *reinterpret_cast<const float4*>(&Kls[e0 + 3][qp]);
#pragma unroll
        for (int i = 0; i < 9; ++i)
          if (i < nrows) {
            const float4 uq = *reinterpret_cast<const float4*>(&U[krow0 + i][e0]);
            acc[i] = fma4(uq.x, K0, fma4(uq.y, K1, fma4(uq.z, K2, fma4(uq.w, K3, acc[i]))));
          }
      }

      // v = mu / (KTu + TINY), write to slot buffer
      float4 vq[9];
#pragma unroll
      for (int i = 0; i < 9; ++i)
        if (i < nrows) {
          vq[i].x = mu4[i].x * __builtin_amdgcn_rcpf(acc[i].x + TINYF);
          vq[i].y = mu4[i].y * __builtin_amdgcn_rcpf(acc[i].y + TINYF);
          vq[i].z = mu4[i].z * __builtin_amdgcn_rcpf(acc[i].z + TINYF);
          vq[i].w = mu4[i].w * __builtin_amdgcn_rcpf(acc[i].w + TINYF);
        }
      asm volatile("s_waitcnt lgkmcnt(0)" ::: "memory");
#pragma unroll
      for (int i = 0; i < 9; ++i)
        if (i < nrows)
          *reinterpret_cast<float4*>(&U[krow0 + i][d4]) = vq[i];
      asm volatile("s_waitcnt lgkmcnt(0)" ::: "memory");

      // ---------- MM2: Kv[k][d] = sum_e K[d][e] * v[k][e]  (dot form, e g-split) ----------
      float4 a2[KN];
#pragma unroll
      for (int k = 0; k < KN; ++k) a2[k] = make_float4(0.f, 0.f, 0.f, 0.f);
      for (int rq = 0; rq < 16; ++rq) {
        const int eqp = rq + (g << 4);
        const int e0 = eqp << 2;
        const int qp = ((eqp ^ m) << 2);
        const float4 Kr0 = *reinterpret_cast<const float4*>(&Kls[d4 + 0][qp]);
        const float4 Kr1 = *reinterpret_cast<const float4*>(&Kls[d4 + 1][qp]);
        const float4 Kr2 = *reinterpret_cast<const float4*>(&Kls[d4 + 2][qp]);
        const float4 Kr3 = *reinterpret_cast<const float4*>(&Kls[d4 + 3][qp]);
#pragma unroll
        for (int k = 0; k < KN; ++k) {
          const float4 vk = *reinterpret_cast<const float4*>(&U[k][e0]);
          a2[k].x = fmaf(vk.w, Kr0.w, fmaf(vk.z, Kr0.z, fmaf(vk.y, Kr0.y, fmaf(vk.x, Kr0.x, a2[k].x))));
          a2[k].y = fmaf(vk.w, Kr1.w, fmaf(vk.z, Kr1.z, fmaf(vk.y, Kr1.y, fmaf(vk.x, Kr1.x, a2[k].y))));
          a2[k].z = fmaf(vk.w, Kr2.w, fmaf(vk.z, Kr2.z, fmaf(vk.y, Kr2.y, fmaf(vk.x, Kr2.x, a2[k].z))));
          a2[k].w = fmaf(vk.w, Kr3.w, fmaf(vk.z, Kr3.z, fmaf(vk.y, Kr3.y, fmaf(vk.x, Kr3.x, a2[k].w))));
        }
      }
      // combine e-halves
#pragma unroll
      for (int k = 0; k < KN; ++k) {
        a2[k].x += __shfl_xor(a2[k].x, 32, 64);
        a2[k].y += __shfl_xor(a2[k].y, 32, 64);
        a2[k].z += __shfl_xor(a2[k].z, 32, 64);
        a2[k].w += __shfl_xor(a2[k].w, 32, 64);
      }

      // b = exp2( (1/17) * sum_k log2(Kv + TINY) )   (log-sum g-split over rows)
      float4 part = make_float4(0.f, 0.f, 0.f, 0.f);
#pragma unroll
      for (int i = 0; i < 9; ++i)
        if (i < nrows) {
          const int k = krow0 + i;
          a2[k].x += TINYF; a2[k].y += TINYF; a2[k].z += TINYF; a2[k].w += TINYF;
          part.x += __builtin_amdgcn_logf(a2[k].x);
          part.y += __builtin_amdgcn_logf(a2[k].y);
          part.z += __builtin_amdgcn_logf(a2[k].z);
          part.w += __builtin_amdgcn_logf(a2[k].w);
        }
      part.x += __shfl_xor(part.x, 32, 64);
      part.y += __shfl_xor(part.y, 32, 64);
      part.z += __shfl_xor(part.z, 32, 64);
      part.w += __shfl_xor(part.w, 32, 64);
      const float w17 = 1.0f / 17.0f;
      bvec = make_float4(__builtin_amdgcn_exp2f(part.x * w17),
                         __builtin_amdgcn_exp2f(part.y * w17),
                         __builtin_amdgcn_exp2f(part.z * w17),
                         __builtin_amdgcn_exp2f(part.w * w17));

      // u = b / (Kv + TINY) for own rows, write back
      asm volatile("s_waitcnt lgkmcnt(0)" ::: "memory");
#pragma unroll
      for (int i = 0; i < 9; ++i)
        if (i < nrows) {
          const int k = krow0 + i;
          float4 uq;
          uq.x = bvec.x * __builtin_amdgcn_rcpf(a2[k].x);
          uq.y = bvec.y * __builtin_amdgcn_rcpf(a2[k].y);
          uq.z = bvec.z * __builtin_amdgcn_rcpf(a2[k].z);
          uq.w = bvec.w * __builtin_amdgcn_rcpf(a2[k].w);
          *reinterpret_cast<float4*>(&U[k][d4]) = uq;
        }
      asm volatile("s_waitcnt lgkmcnt(0)" ::: "memory");
    }

    if (g == 0)
      *reinterpret_cast<float4*>(&Xout[(long)n * D + d4]) = bvec;
  }
}

extern "C" void kernel_launch(void* const* d_in, const int* in_sizes, int n_in,
                              void* d_out, int out_size, void* d_ws, size_t ws_size,
                              hipStream_t stream) {
  const float* trans_X = (const float*)d_in[0];
  const float* cost = (const float*)d_in[1];
  const int* neigh = (const int*)d_in[2];
  float* out = (float*)d_out;
  float* X1 = (float*)d_ws;   // intermediate hop output, 20000*128 f32 = 10.24 MB
  const int n = in_sizes[0] / D;

  // 250 blocks x 8 slots = 2000 slots -> exactly 10 nodes per slot (balanced)
  dim3 grid(250), block(512);
  hipLaunchKernelGGL(wgcn_hop, grid, block, 0, stream, trans_X, cost, neigh, X1, n);
  hipLaunchKernelGGL(wgcn_hop, grid, block, 0, stream, X1, cost, neigh, out, n);
}

// Round 6
// 11890.221 us; speedup vs baseline: 1.3470x; 1.3449x over previous
//
#include <hip/hip_runtime.h>

#define D 128
#define KN 17
#define NEIGH 16
#define SINKI 20
#define TINYF 1e-30f

__device__ __forceinline__ float4 fma4(float a, const float4 b, const float4 c) {
  return make_float4(fmaf(a, b.x, c.x), fmaf(a, b.y, c.y),
                     fmaf(a, b.z, c.z), fmaf(a, b.w, c.w));
}

// block = 512 threads = 8 node-slots of one wave each.
// LDS: swizzled K (64KB) + 8 slot-buffers (17x128 f32) = 132 KB.
// K[e][d] stored at row e, quad (d>>2)^((e>>2)&31)  (quad-bijective XOR tiling,
// measured conflict-free in round 5). Each 32-lane half owns rows krow0..krow0+nrows-1
// for BOTH matmuls; register arrays are indexed ONLY by static i (krow0 enters LDS
// addresses only) -- avoids the round-5 runtime-index -> scratch catastrophe.
__global__ __launch_bounds__(512, 1)
void wgcn_hop(const float* __restrict__ Xin,
              const float* __restrict__ Cmat,
              const int* __restrict__ neigh,
              float* __restrict__ Xout,
              int n_nodes) {
  __shared__ float Kls[D][D];
  __shared__ float ubuf[8][KN][D];

  const int tid = threadIdx.x;

  // ---- stage swizzled Gibbs kernel (once per block) ----
  for (int base = tid * 4; base < D * D; base += 2048) {
    const int r = base >> 7;
    const int c0 = base & 127;
    float4 cv = *reinterpret_cast<const float4*>(&Cmat[base]);
    float4 kv;
    kv.x = expf(-cv.x / 0.1f);
    kv.y = expf(-cv.y / 0.1f);
    kv.z = expf(-cv.z / 0.1f);
    kv.w = expf(-cv.w / 0.1f);
    const int qp = (((c0 >> 2) ^ ((r >> 2) & 31)) << 2);
    *reinterpret_cast<float4*>(&Kls[r][qp]) = kv;
  }
  __syncthreads();

  const int slot = tid >> 6;      // node slot (one wave)
  const int lane = tid & 63;
  const int g = lane >> 5;        // half: owns rows 0..8 (g=0) or 9..16 (g=1)
  const int m = lane & 31;        // column-quad index
  const int d4 = m << 2;
  const int nrows = g ? (KN - 9) : 9;
  const int krow0 = g ? 9 : 0;
  float (*U)[D] = ubuf[slot];

  const int slot_id = blockIdx.x * 8 + slot;
  const int slot_cnt = gridDim.x * 8;

  for (int n = slot_id; n < n_nodes; n += slot_cnt) {
    float4 mu4[9];
    float4 bvec = make_float4(0.f, 0.f, 0.f, 0.f);

    // ---- gather neighbor distributions, row-normalize; u0 = 1 ----
#pragma unroll
    for (int i = 0; i < 9; ++i) {
      if (i < nrows) {
        const int k = krow0 + i;
        const int src = (k < NEIGH) ? neigh[n * NEIGH + k] : n;
        float4 x = *reinterpret_cast<const float4*>(&Xin[(long)src * D + d4]);
        float s = x.x + x.y + x.z + x.w;
        s += __shfl_xor(s, 16, 64);
        s += __shfl_xor(s, 8, 64);
        s += __shfl_xor(s, 4, 64);
        s += __shfl_xor(s, 2, 64);
        s += __shfl_xor(s, 1, 64);
        const float inv = __builtin_amdgcn_rcpf(s + TINYF);
        mu4[i] = make_float4(x.x * inv, x.y * inv, x.z * inv, x.w * inv);
        *reinterpret_cast<float4*>(&U[k][d4]) = make_float4(1.f, 1.f, 1.f, 1.f);
      }
    }
    asm volatile("s_waitcnt lgkmcnt(0)" ::: "memory");

    for (int it = 0; it < SINKI; ++it) {
      // ---------- MM1: KTu[k][d4..d4+3] = sum_e u[k][e] * K[e][d]  (own rows) ----------
      float4 acc[9];
#pragma unroll
      for (int i = 0; i < 9; ++i) acc[i] = make_float4(0.f, 0.f, 0.f, 0.f);
#pragma unroll 2
      for (int eq = 0; eq < 32; ++eq) {
        const int e0 = eq << 2;
        const int qp = ((m ^ eq) << 2);
        const float4 K0 = *reinterpret_cast<const float4*>(&Kls[e0 + 0][qp]);
        const float4 K1 = *reinterpret_cast<const float4*>(&Kls[e0 + 1][qp]);
        const float4 K2 = *reinterpret_cast<const float4*>(&Kls[e0 + 2][qp]);
        const float4 K3 = *reinterpret_cast<const float4*>(&Kls[e0 + 3][qp]);
#pragma unroll
        for (int i = 0; i < 9; ++i)
          if (i < nrows) {
            const float4 uq = *reinterpret_cast<const float4*>(&U[krow0 + i][e0]);
            acc[i] = fma4(uq.x, K0, fma4(uq.y, K1, fma4(uq.z, K2, fma4(uq.w, K3, acc[i]))));
          }
      }

      // v = mu / (KTu + TINY), write own rows back (full width across m)
      asm volatile("s_waitcnt lgkmcnt(0)" ::: "memory");
#pragma unroll
      for (int i = 0; i < 9; ++i)
        if (i < nrows) {
          float4 vq;
          vq.x = mu4[i].x * __builtin_amdgcn_rcpf(acc[i].x + TINYF);
          vq.y = mu4[i].y * __builtin_amdgcn_rcpf(acc[i].y + TINYF);
          vq.z = mu4[i].z * __builtin_amdgcn_rcpf(acc[i].z + TINYF);
          vq.w = mu4[i].w * __builtin_amdgcn_rcpf(acc[i].w + TINYF);
          *reinterpret_cast<float4*>(&U[krow0 + i][d4]) = vq;
        }
      asm volatile("s_waitcnt lgkmcnt(0)" ::: "memory");

      // ---------- MM2: Kv[k][d4+c] = sum_e K[d4+c][e] * v[k][e]  (own rows, full e) ----------
      float4 a2[9];
#pragma unroll
      for (int i = 0; i < 9; ++i) a2[i] = make_float4(0.f, 0.f, 0.f, 0.f);
#pragma unroll 2
      for (int eq = 0; eq < 32; ++eq) {
        const int e0 = eq << 2;
        const int qp = ((eq ^ m) << 2);
        const float4 Kr0 = *reinterpret_cast<const float4*>(&Kls[d4 + 0][qp]);
        const float4 Kr1 = *reinterpret_cast<const float4*>(&Kls[d4 + 1][qp]);
        const float4 Kr2 = *reinterpret_cast<const float4*>(&Kls[d4 + 2][qp]);
        const float4 Kr3 = *reinterpret_cast<const float4*>(&Kls[d4 + 3][qp]);
#pragma unroll
        for (int i = 0; i < 9; ++i)
          if (i < nrows) {
            const float4 vk = *reinterpret_cast<const float4*>(&U[krow0 + i][e0]);
            a2[i].x = fmaf(vk.w, Kr0.w, fmaf(vk.z, Kr0.z, fmaf(vk.y, Kr0.y, fmaf(vk.x, Kr0.x, a2[i].x))));
            a2[i].y = fmaf(vk.w, Kr1.w, fmaf(vk.z, Kr1.z, fmaf(vk.y, Kr1.y, fmaf(vk.x, Kr1.x, a2[i].y))));
            a2[i].z = fmaf(vk.w, Kr2.w, fmaf(vk.z, Kr2.z, fmaf(vk.y, Kr2.y, fmaf(vk.x, Kr2.x, a2[i].z))));
            a2[i].w = fmaf(vk.w, Kr3.w, fmaf(vk.z, Kr3.z, fmaf(vk.y, Kr3.y, fmaf(vk.x, Kr3.x, a2[i].w))));
          }
      }

      // b = exp2( (1/17) * sum_k log2(Kv + TINY) )  (own-rows partial, then cross-half)
      float4 part = make_float4(0.f, 0.f, 0.f, 0.f);
#pragma unroll
      for (int i = 0; i < 9; ++i)
        if (i < nrows) {
          a2[i].x += TINYF; a2[i].y += TINYF; a2[i].z += TINYF; a2[i].w += TINYF;
          part.x += __builtin_amdgcn_logf(a2[i].x);
          part.y += __builtin_amdgcn_logf(a2[i].y);
          part.z += __builtin_amdgcn_logf(a2[i].z);
          part.w += __builtin_amdgcn_logf(a2[i].w);
        }
      part.x += __shfl_xor(part.x, 32, 64);
      part.y += __shfl_xor(part.y, 32, 64);
      part.z += __shfl_xor(part.z, 32, 64);
      part.w += __shfl_xor(part.w, 32, 64);
      const float w17 = 1.0f / 17.0f;
      bvec = make_float4(__builtin_amdgcn_exp2f(part.x * w17),
                         __builtin_amdgcn_exp2f(part.y * w17),
                         __builtin_amdgcn_exp2f(part.z * w17),
                         __builtin_amdgcn_exp2f(part.w * w17));

      // u = b / (Kv + TINY) for own rows, write back
      asm volatile("s_waitcnt lgkmcnt(0)" ::: "memory");
#pragma unroll
      for (int i = 0; i < 9; ++i)
        if (i < nrows) {
          float4 uq;
          uq.x = bvec.x * __builtin_amdgcn_rcpf(a2[i].x);
          uq.y = bvec.y * __builtin_amdgcn_rcpf(a2[i].y);
          uq.z = bvec.z * __builtin_amdgcn_rcpf(a2[i].z);
          uq.w = bvec.w * __builtin_amdgcn_rcpf(a2[i].w);
          *reinterpret_cast<float4*>(&U[krow0 + i][d4]) = uq;
        }
      asm volatile("s_waitcnt lgkmcnt(0)" ::: "memory");
    }

    if (g == 0)
      *reinterpret_cast<float4*>(&Xout[(long)n * D + d4]) = bvec;
  }
}

extern "C" void kernel_launch(void* const* d_in, const int* in_sizes, int n_in,
                              void* d_out, int out_size, void* d_ws, size_t ws_size,
                              hipStream_t stream) {
  const float* trans_X = (const float*)d_in[0];
  const float* cost = (const float*)d_in[1];
  const int* neigh = (const int*)d_in[2];
  float* out = (float*)d_out;
  float* X1 = (float*)d_ws;   // intermediate hop output, 20000*128 f32 = 10.24 MB
  const int n = in_sizes[0] / D;

  // 250 blocks x 8 slots = 2000 slots -> exactly 10 nodes per slot (balanced)
  dim3 grid(250), block(512);
  hipLaunchKernelGGL(wgcn_hop, grid, block, 0, stream, trans_X, cost, neigh, X1, n);
  hipLaunchKernelGGL(wgcn_hop, grid, block, 0, stream, X1, cost, neigh, out, n);
}

// Round 7
// 2184.831 us; speedup vs baseline: 7.3305x; 5.4422x over previous
//
#include <hip/hip_runtime.h>

#define D 128
#define KN 17
#define NEIGH 16
#define SINKI 20
#define TINYF 1e-30f

typedef __attribute__((ext_vector_type(8))) _Float16 f16x8;
typedef __attribute__((ext_vector_type(4))) float f32x4;
typedef __attribute__((ext_vector_type(2))) unsigned int u32x2;

// DPP rotate within 16-lane row: ror by N lanes.
template <int N>
__device__ __forceinline__ float rorf(float v) {
  int r = __builtin_amdgcn_update_dpp(0, __builtin_bit_cast(int, v),
                                      0x120 + N, 0xf, 0xf, true);
  return __builtin_bit_cast(float, r);
}

__device__ __forceinline__ f16x8 ldfrag(const _Float16* U, int k, int ks, int g) {
  // US[k][e], e = 32ks + 8g + s (s=0..7 contiguous); byte-swizzle ^= (k&15)<<4
  return *(const f16x8*)((const char*)U + k * 256 + (((ks << 6) + (g << 4)) ^ ((k & 15) << 4)));
}

__device__ __forceinline__ void stquad(_Float16* U, int k, int rt, int g,
                                       float x, float y, float z, float w) {
  // write US[k][d0..d0+3], d0 = 16rt + 4g, same swizzle; 8B aligned
  union { _Float16 h[4]; u32x2 u; } P;
  P.h[0] = (_Float16)x; P.h[1] = (_Float16)y; P.h[2] = (_Float16)z; P.h[3] = (_Float16)w;
  *(u32x2*)((char*)U + k * 256 + (((rt << 5) + (g << 3)) ^ ((k & 15) << 4))) = P.u;
}

// block = 512 threads = 8 node-slots (1 wave each). LDS = 128 KB:
//  KB: MM1 A-frags: tile(ks,rt), lane(g*16+c), slot s -> Khat[e=32ks+8g+s][d=16rt+c]
//  KA: MM2 A-frags: ...                               -> Khat[d=16rt+c][e=32ks+8g+s]
//  US: per-slot u/v, [32 rows k][128 e] f16, rows 17..31 pad = 0, XOR-swizzled.
// Scaling: Khat = 16*K, muhat = 1024*mu -> all f16-normal; cancels in Sinkhorn
// ratios; output b = bhat/1024.
__global__ __launch_bounds__(512, 1)
void wgcn_hop(const float* __restrict__ Xin,
              const float* __restrict__ Cmat,
              const int* __restrict__ neigh,
              float* __restrict__ Xout,
              int n_nodes) {
  __shared__ _Float16 KB[16384];
  __shared__ _Float16 KA[16384];
  __shared__ _Float16 US[8][4096];

  const int tid = threadIdx.x;

  // ---- stage fragment-ordered Gibbs kernel (once per block) ----
  for (int idx = tid; idx < 16384; idx += 512) {
    const int s = idx & 7, c = (idx >> 3) & 15, g = (idx >> 7) & 3;
    const int rt = (idx >> 9) & 7, ks = idx >> 12;
    const int e = (ks << 5) + (g << 3) + s;
    const int d = (rt << 4) + c;
    KB[idx] = (_Float16)(16.0f * expf(-10.0f * Cmat[e * 128 + d]));
    KA[idx] = (_Float16)(16.0f * expf(-10.0f * Cmat[d * 128 + e]));
  }
  __syncthreads();

  const int slot = tid >> 6;
  const int lane = tid & 63;
  const int g = lane >> 4;     // 4-lane group (C/D row nibble, DPP row = 16 lanes)
  const int c = lane & 15;     // column-in-tile / k-row low nibble
  _Float16* U = US[slot];

  const int slot_id = blockIdx.x * 8 + slot;
  const int slot_cnt = gridDim.x * 8;

  for (int n = slot_id; n < n_nodes; n += slot_cnt) {
    // ---- gather mu in D-frag layout: mu[k][d], k=16ct+c, d=16rt+4g+r ----
    f32x4 mu0[8], mu1[8], bv[8];
    const int src0 = neigh[n * NEIGH + c];
#pragma unroll
    for (int rt = 0; rt < 8; ++rt) {
      mu0[rt] = *(const f32x4*)&Xin[src0 * D + rt * 16 + g * 4];
      mu1[rt] = *(const f32x4*)&Xin[n * D + rt * 16 + g * 4];
    }
    float s0 = 0.f, s1 = 0.f;
#pragma unroll
    for (int rt = 0; rt < 8; ++rt) {
      s0 += mu0[rt].x + mu0[rt].y + mu0[rt].z + mu0[rt].w;
      s1 += mu1[rt].x + mu1[rt].y + mu1[rt].z + mu1[rt].w;
    }
    s0 += __shfl_xor(s0, 16, 64); s0 += __shfl_xor(s0, 32, 64);
    s1 += __shfl_xor(s1, 16, 64); s1 += __shfl_xor(s1, 32, 64);
    float i0 = 1024.0f * __builtin_amdgcn_rcpf(s0 + TINYF);
    float i1 = 1024.0f * __builtin_amdgcn_rcpf(s1 + TINYF);
    if (c != 0) i1 = 0.f;   // pad rows k=17..31 get mu=0
#pragma unroll
    for (int rt = 0; rt < 8; ++rt) {
      mu0[rt].x *= i0; mu0[rt].y *= i0; mu0[rt].z *= i0; mu0[rt].w *= i0;
      mu1[rt].x *= i1; mu1[rt].y *= i1; mu1[rt].z *= i1; mu1[rt].w *= i1;
    }

    // ---- u0 = 1 on real rows, 0 on pad rows (swizzle is row-internal) ----
#pragma unroll
    for (int j = 0; j < 32; ++j)
      ((unsigned int*)U)[(j << 6) | lane] = (j < KN) ? 0x3C003C00u : 0u;
    asm volatile("s_waitcnt lgkmcnt(0)" ::: "memory");

#pragma unroll 1
    for (int it = 0; it < SINKI; ++it) {
      // ======== MM1': D1'[d][k] = sum_e Khat[e][d] * u[k][e] ========
      f16x8 bf0[4], bf1[4];
#pragma unroll
      for (int ks = 0; ks < 4; ++ks) {
        bf0[ks] = ldfrag(U, c, ks, g);
        bf1[ks] = ldfrag(U, 16 + c, ks, g);
      }
#pragma unroll
      for (int rt = 0; rt < 8; ++rt) {
        f32x4 a0 = {0.f, 0.f, 0.f, 0.f}, a1 = {0.f, 0.f, 0.f, 0.f};
#pragma unroll
        for (int ks = 0; ks < 4; ++ks) {
          const f16x8 af = *(const f16x8*)&KB[((((ks << 3) + rt) << 6) + lane) << 3];
          a0 = __builtin_amdgcn_mfma_f32_16x16x32_f16(af, bf0[ks], a0, 0, 0, 0);
          a1 = __builtin_amdgcn_mfma_f32_16x16x32_f16(af, bf1[ks], a1, 0, 0, 0);
        }
        // vhat = muhat * rcp(KTu' + tiny); write back (pad k: mu=0 -> v=0)
        stquad(U, c, rt, g,
               mu0[rt].x * __builtin_amdgcn_rcpf(a0.x + TINYF),
               mu0[rt].y * __builtin_amdgcn_rcpf(a0.y + TINYF),
               mu0[rt].z * __builtin_amdgcn_rcpf(a0.z + TINYF),
               mu0[rt].w * __builtin_amdgcn_rcpf(a0.w + TINYF));
        stquad(U, 16 + c, rt, g,
               mu1[rt].x * __builtin_amdgcn_rcpf(a1.x + TINYF),
               mu1[rt].y * __builtin_amdgcn_rcpf(a1.y + TINYF),
               mu1[rt].z * __builtin_amdgcn_rcpf(a1.z + TINYF),
               mu1[rt].w * __builtin_amdgcn_rcpf(a1.w + TINYF));
      }
      asm volatile("s_waitcnt lgkmcnt(0)" ::: "memory");

      // ======== MM2': D2'[d][k] = sum_e Khat[d][e] * vhat[k][e] ========
#pragma unroll
      for (int ks = 0; ks < 4; ++ks) {
        bf0[ks] = ldfrag(U, c, ks, g);
        bf1[ks] = ldfrag(U, 16 + c, ks, g);
      }
#pragma unroll
      for (int rt = 0; rt < 8; ++rt) {
        f32x4 a0 = {0.f, 0.f, 0.f, 0.f}, a1 = {0.f, 0.f, 0.f, 0.f};
#pragma unroll
        for (int ks = 0; ks < 4; ++ks) {
          const f16x8 af = *(const f16x8*)&KA[((((ks << 3) + rt) << 6) + lane) << 3];
          a0 = __builtin_amdgcn_mfma_f32_16x16x32_f16(af, bf0[ks], a0, 0, 0, 0);
          a1 = __builtin_amdgcn_mfma_f32_16x16x32_f16(af, bf1[ks], a1, 0, 0, 0);
        }
        // b = exp2( (1/17) * sum_k log2(Kv + tiny) ), k=16 term folded in at c==0
        f32x4 bq;
#pragma unroll
        for (int r = 0; r < 4; ++r) {
          const float t0 = ((const float*)&a0)[r] + TINYF;
          const float t1 = ((const float*)&a1)[r] + TINYF;
          float t = (c == 0) ? t0 * t1 : t0;
          float p = __builtin_amdgcn_logf(t);
          p += rorf<1>(p); p += rorf<2>(p); p += rorf<4>(p); p += rorf<8>(p);
          ((float*)&bq)[r] = __builtin_amdgcn_exp2f(p * (1.0f / 17.0f));
        }
        bv[rt] = bq;
        // u = b * rcp(Kv + tiny); pad k (ct=1, c>0) forced to 0
        stquad(U, c, rt, g,
               bq.x * __builtin_amdgcn_rcpf(a0.x + TINYF),
               bq.y * __builtin_amdgcn_rcpf(a0.y + TINYF),
               bq.z * __builtin_amdgcn_rcpf(a0.z + TINYF),
               bq.w * __builtin_amdgcn_rcpf(a0.w + TINYF));
        const float m1 = (c == 0) ? 1.f : 0.f;
        stquad(U, 16 + c, rt, g,
               m1 * bq.x * __builtin_amdgcn_rcpf(a1.x + TINYF),
               m1 * bq.y * __builtin_amdgcn_rcpf(a1.y + TINYF),
               m1 * bq.z * __builtin_amdgcn_rcpf(a1.z + TINYF),
               m1 * bq.w * __builtin_amdgcn_rcpf(a1.w + TINYF));
      }
      asm volatile("s_waitcnt lgkmcnt(0)" ::: "memory");
    }

    // ---- output: b = bhat / 1024; lanes c==0 hold every d = 16rt+4g+r ----
    if (c == 0) {
#pragma unroll
      for (int rt = 0; rt < 8; ++rt) {
        f32x4 o = bv[rt];
        o.x *= (1.0f / 1024.0f); o.y *= (1.0f / 1024.0f);
        o.z *= (1.0f / 1024.0f); o.w *= (1.0f / 1024.0f);
        *(f32x4*)&Xout[n * D + rt * 16 + g * 4] = o;
      }
    }
  }
}

extern "C" void kernel_launch(void* const* d_in, const int* in_sizes, int n_in,
                              void* d_out, int out_size, void* d_ws, size_t ws_size,
                              hipStream_t stream) {
  const float* trans_X = (const float*)d_in[0];
  const float* cost = (const float*)d_in[1];
  const int* neigh = (const int*)d_in[2];
  float* out = (float*)d_out;
  float* X1 = (float*)d_ws;   // intermediate hop output, 20000*128 f32
  const int n = in_sizes[0] / D;

  // 250 blocks x 8 slots = 2000 slots -> 10 nodes per slot
  dim3 grid(250), block(512);
  hipLaunchKernelGGL(wgcn_hop, grid, block, 0, stream, trans_X, cost, neigh, X1, n);
  hipLaunchKernelGGL(wgcn_hop, grid, block, 0, stream, X1, cost, neigh, out, n);
}

// Round 11
// 1777.325 us; speedup vs baseline: 9.0112x; 1.2293x over previous
//
#include <hip/hip_runtime.h>

#define D 128
#define NEIGH 16
#define SINKI 20
#define TINYF 1e-30f

typedef __attribute__((ext_vector_type(8))) _Float16 f16x8;
typedef __attribute__((ext_vector_type(2))) _Float16 f16x2;
typedef __attribute__((ext_vector_type(4))) float f32x4;
typedef __attribute__((ext_vector_type(2))) unsigned int u32x2;

// DPP rotate within 16-lane row: ror by N lanes, accumulate -> full row sum.
template <int N>
__device__ __forceinline__ float rorf(float v) {
  int r = __builtin_amdgcn_update_dpp(0, __builtin_bit_cast(int, v),
                                      0x120 + N, 0xf, 0xf, true);
  return __builtin_bit_cast(float, r);
}

// U row k (256B), byte-swizzle ^((k&15)<<4); read 16B e-slice (ks,g)
__device__ __forceinline__ f16x8 ldfrag(const _Float16* U, int k, int ks, int g) {
  return *(const f16x8*)((const char*)U + k * 256 + (((ks << 6) + (g << 4)) ^ ((k & 15) << 4)));
}

// write U[k][d0..d0+3], d0 = 16rt+4g, same swizzle; RTE casts (round-7 numerics)
__device__ __forceinline__ void stquad(_Float16* U, int k, int rt, int g,
                                       float x, float y, float z, float w) {
  union { _Float16 h[4]; u32x2 u; } P;
  P.h[0] = (_Float16)x; P.h[1] = (_Float16)y;
  P.h[2] = (_Float16)z; P.h[3] = (_Float16)w;
  *(u32x2*)((char*)U + k * 256 + (((rt << 5) + (g << 3)) ^ ((k & 15) << 4))) = P.u;
}

// block = 512 thr = 8 slots (1 wave each); each slot processes a PAIR of nodes.
// U rows: 0..15 = node-A neighbors, 16..31 = node-B neighbors, 32 = self A,
// 33 = self B, 34 = permanent zero row (pad reads), 35 = unused pad.
// LDS = KB(32K) + KA(32K) + 8*9K = 136 KB.
__global__ __launch_bounds__(512, 1)
void wgcn_hop(const float* __restrict__ Xin,
              const float* __restrict__ Cmat,
              const int* __restrict__ neigh,
              float* __restrict__ Xout,
              int n_pairs) {
  __shared__ _Float16 KB[16384];   // MM1 A-frags: Khat[e=32ks+8g+s][d=16rt+c]
  __shared__ _Float16 KA[16384];   // MM2 A-frags: Khat[d=16rt+c][e=32ks+8g+s]
  __shared__ _Float16 US[8][4608]; // 36 rows x 128 f16 per slot

  const int tid = threadIdx.x;

  for (int idx = tid; idx < 16384; idx += 512) {
    const int s = idx & 7, c = (idx >> 3) & 15, g = (idx >> 7) & 3;
    const int rt = (idx >> 9) & 7, ks = idx >> 12;
    const int e = (ks << 5) + (g << 3) + s;
    const int d = (rt << 4) + c;
    KB[idx] = (_Float16)(16.0f * expf(-10.0f * Cmat[e * 128 + d]));
    KA[idx] = (_Float16)(16.0f * expf(-10.0f * Cmat[d * 128 + e]));
  }
  __syncthreads();

  const int slot = tid >> 6;
  const int lane = tid & 63;
  const int g = lane >> 4;
  const int c = lane & 15;
  const int cc = (c < 2) ? c : 2;          // tile2 read-row offset (row 34 = zeros)
  _Float16* U = US[slot];

  for (int p = blockIdx.x * 8 + slot; p < n_pairs; p += gridDim.x * 8) {
    const int nA = 2 * p, nB = 2 * p + 1;

    // ---- gather mu for A-neighbors, B-neighbors, selves; normalize ----
    f32x4 mu0[8], mu1[8], muS[8], bvA[8], bvB[8];
    const int srcA = neigh[nA * NEIGH + c];
    const int srcB = neigh[nB * NEIGH + c];
    const int srcS = (c == 1) ? nB : nA;   // c==0 -> A, c==1 -> B, c>=2 dummy
#pragma unroll
    for (int rt = 0; rt < 8; ++rt) {
      mu0[rt] = *(const f32x4*)&Xin[(long)srcA * D + rt * 16 + g * 4];
      mu1[rt] = *(const f32x4*)&Xin[(long)srcB * D + rt * 16 + g * 4];
      muS[rt] = *(const f32x4*)&Xin[(long)srcS * D + rt * 16 + g * 4];
    }
    float s0 = 0.f, s1 = 0.f, sS = 0.f;
#pragma unroll
    for (int rt = 0; rt < 8; ++rt) {
      s0 += mu0[rt].x + mu0[rt].y + mu0[rt].z + mu0[rt].w;
      s1 += mu1[rt].x + mu1[rt].y + mu1[rt].z + mu1[rt].w;
      sS += muS[rt].x + muS[rt].y + muS[rt].z + muS[rt].w;
    }
    s0 += __shfl_xor(s0, 16, 64); s0 += __shfl_xor(s0, 32, 64);
    s1 += __shfl_xor(s1, 16, 64); s1 += __shfl_xor(s1, 32, 64);
    sS += __shfl_xor(sS, 16, 64); sS += __shfl_xor(sS, 32, 64);
    const float i0 = 1024.0f * __builtin_amdgcn_rcpf(s0 + TINYF);
    const float i1 = 1024.0f * __builtin_amdgcn_rcpf(s1 + TINYF);
    const float iS = 1024.0f * __builtin_amdgcn_rcpf(sS + TINYF);
#pragma unroll
    for (int rt = 0; rt < 8; ++rt) {
      mu0[rt].x *= i0; mu0[rt].y *= i0; mu0[rt].z *= i0; mu0[rt].w *= i0;
      mu1[rt].x *= i1; mu1[rt].y *= i1; mu1[rt].z *= i1; mu1[rt].w *= i1;
      muS[rt].x *= iS; muS[rt].y *= iS; muS[rt].z *= iS; muS[rt].w *= iS;
    }

    // ---- u0 = 1 on real rows 0..33, 0 on rows 34/35 ----
#pragma unroll
    for (int j = 0; j < 36; ++j)
      ((unsigned int*)U)[(j << 6) | lane] = (j < 34) ? 0x3C003C00u : 0u;
    asm volatile("s_waitcnt lgkmcnt(0)" ::: "memory");

#pragma unroll 1
    for (int it = 0; it < SINKI; ++it) {
      // ======== MM1': KTu'[d][k] = sum_e Khat[e][d] * u[k][e] ========
      f16x8 b0[4], b1[4], b2[4];
#pragma unroll
      for (int ks = 0; ks < 4; ++ks) {
        b0[ks] = ldfrag(U, c, ks, g);
        b1[ks] = ldfrag(U, 16 + c, ks, g);
        b2[ks] = ldfrag(U, 32 + cc, ks, g);
      }
#pragma unroll
      for (int rt = 0; rt < 8; ++rt) {
        f32x4 a0 = {0.f, 0.f, 0.f, 0.f}, a1 = a0, a2 = a0;
#pragma unroll
        for (int ks = 0; ks < 4; ++ks) {
          const f16x8 af = *(const f16x8*)&KB[((((ks << 3) + rt) << 6) + lane) << 3];
          a0 = __builtin_amdgcn_mfma_f32_16x16x32_f16(af, b0[ks], a0, 0, 0, 0);
          a1 = __builtin_amdgcn_mfma_f32_16x16x32_f16(af, b1[ks], a1, 0, 0, 0);
          a2 = __builtin_amdgcn_mfma_f32_16x16x32_f16(af, b2[ks], a2, 0, 0, 0);
        }
        stquad(U, c, rt, g,
               mu0[rt].x * __builtin_amdgcn_rcpf(a0.x + TINYF),
               mu0[rt].y * __builtin_amdgcn_rcpf(a0.y + TINYF),
               mu0[rt].z * __builtin_amdgcn_rcpf(a0.z + TINYF),
               mu0[rt].w * __builtin_amdgcn_rcpf(a0.w + TINYF));
        stquad(U, 16 + c, rt, g,
               mu1[rt].x * __builtin_amdgcn_rcpf(a1.x + TINYF),
               mu1[rt].y * __builtin_amdgcn_rcpf(a1.y + TINYF),
               mu1[rt].z * __builtin_amdgcn_rcpf(a1.z + TINYF),
               mu1[rt].w * __builtin_amdgcn_rcpf(a1.w + TINYF));
        if (c < 2)
          stquad(U, 32 + c, rt, g,
                 muS[rt].x * __builtin_amdgcn_rcpf(a2.x + TINYF),
                 muS[rt].y * __builtin_amdgcn_rcpf(a2.y + TINYF),
                 muS[rt].z * __builtin_amdgcn_rcpf(a2.z + TINYF),
                 muS[rt].w * __builtin_amdgcn_rcpf(a2.w + TINYF));
      }
      asm volatile("s_waitcnt lgkmcnt(0)" ::: "memory");

      // ======== MM2': Kv'[d][k] = sum_e Khat[d][e] * v[k][e] ========
#pragma unroll
      for (int ks = 0; ks < 4; ++ks) {
        b0[ks] = ldfrag(U, c, ks, g);
        b1[ks] = ldfrag(U, 16 + c, ks, g);
        b2[ks] = ldfrag(U, 32 + cc, ks, g);
      }
#pragma unroll
      for (int rt = 0; rt < 8; ++rt) {
        f32x4 a0 = {0.f, 0.f, 0.f, 0.f}, a1 = a0, a2 = a0;
#pragma unroll
        for (int ks = 0; ks < 4; ++ks) {
          const f16x8 af = *(const f16x8*)&KA[((((ks << 3) + rt) << 6) + lane) << 3];
          a0 = __builtin_amdgcn_mfma_f32_16x16x32_f16(af, b0[ks], a0, 0, 0, 0);
          a1 = __builtin_amdgcn_mfma_f32_16x16x32_f16(af, b1[ks], a1, 0, 0, 0);
          a2 = __builtin_amdgcn_mfma_f32_16x16x32_f16(af, b2[ks], a2, 0, 0, 0);
        }
        float bA[4], bB[4];
#pragma unroll
        for (int r = 0; r < 4; ++r) {
          const float tA = ((const float*)&a0)[r] + TINYF;
          const float tB = ((const float*)&a1)[r] + TINYF;
          const float tS = ((const float*)&a2)[r] + TINYF;
          float fA = (c == 0) ? tA * tS : tA;   // fold self-A into lane c==0
          float fB = (c == 1) ? tB * tS : tB;   // fold self-B into lane c==1
          float pA = __builtin_amdgcn_logf(fA);
          float pB = __builtin_amdgcn_logf(fB);
          pA += rorf<1>(pA); pA += rorf<2>(pA); pA += rorf<4>(pA); pA += rorf<8>(pA);
          pB += rorf<1>(pB); pB += rorf<2>(pB); pB += rorf<4>(pB); pB += rorf<8>(pB);
          bA[r] = __builtin_amdgcn_exp2f(pA * (1.0f / 17.0f));
          bB[r] = __builtin_amdgcn_exp2f(pB * (1.0f / 17.0f));
        }
        bvA[rt].x = bA[0]; bvA[rt].y = bA[1]; bvA[rt].z = bA[2]; bvA[rt].w = bA[3];
        bvB[rt].x = bB[0]; bvB[rt].y = bB[1]; bvB[rt].z = bB[2]; bvB[rt].w = bB[3];
        stquad(U, c, rt, g,
               bA[0] * __builtin_amdgcn_rcpf(((const float*)&a0)[0] + TINYF),
               bA[1] * __builtin_amdgcn_rcpf(((const float*)&a0)[1] + TINYF),
               bA[2] * __builtin_amdgcn_rcpf(((const float*)&a0)[2] + TINYF),
               bA[3] * __builtin_amdgcn_rcpf(((const float*)&a0)[3] + TINYF));
        stquad(U, 16 + c, rt, g,
               bB[0] * __builtin_amdgcn_rcpf(((const float*)&a1)[0] + TINYF),
               bB[1] * __builtin_amdgcn_rcpf(((const float*)&a1)[1] + TINYF),
               bB[2] * __builtin_amdgcn_rcpf(((const float*)&a1)[2] + TINYF),
               bB[3] * __builtin_amdgcn_rcpf(((const float*)&a1)[3] + TINYF));
        if (c < 2) {
          const float q0 = ((c == 0) ? bA[0] : bB[0]) * __builtin_amdgcn_rcpf(((const float*)&a2)[0] + TINYF);
          const float q1 = ((c == 0) ? bA[1] : bB[1]) * __builtin_amdgcn_rcpf(((const float*)&a2)[1] + TINYF);
          const float q2 = ((c == 0) ? bA[2] : bB[2]) * __builtin_amdgcn_rcpf(((const float*)&a2)[2] + TINYF);
          const float q3 = ((c == 0) ? bA[3] : bB[3]) * __builtin_amdgcn_rcpf(((const float*)&a2)[3] + TINYF);
          stquad(U, 32 + c, rt, g, q0, q1, q2, q3);
        }
      }
      asm volatile("s_waitcnt lgkmcnt(0)" ::: "memory");
    }

    // ---- output: lane c==0 -> node A, c==1 -> node B; b = bhat/1024 (f32 path) ----
    if (c < 2) {
      float* dst = &Xout[(long)((c == 0) ? nA : nB) * D];
#pragma unroll
      for (int rt = 0; rt < 8; ++rt) {
        const f32x4 bq = (c == 0) ? bvA[rt] : bvB[rt];
        f32x4 o;
        o.x = bq.x * (1.0f / 1024.0f);
        o.y = bq.y * (1.0f / 1024.0f);
        o.z = bq.z * (1.0f / 1024.0f);
        o.w = bq.w * (1.0f / 1024.0f);
        *(f32x4*)&dst[rt * 16 + g * 4] = o;
      }
    }
  }
}

extern "C" void kernel_launch(void* const* d_in, const int* in_sizes, int n_in,
                              void* d_out, int out_size, void* d_ws, size_t ws_size,
                              hipStream_t stream) {
  const float* trans_X = (const float*)d_in[0];
  const float* cost = (const float*)d_in[1];
  const int* neigh = (const int*)d_in[2];
  float* out = (float*)d_out;
  float* X1 = (float*)d_ws;   // intermediate hop output, 20000*128 f32
  const int n = in_sizes[0] / D;
  const int n_pairs = n / 2;  // N = 20000 even

  // 250 blocks x 8 slots = 2000 slots -> exactly 5 pairs per slot
  dim3 grid(250), block(512);
  hipLaunchKernelGGL(wgcn_hop, grid, block, 0, stream, trans_X, cost, neigh, X1, n_pairs);
  hipLaunchKernelGGL(wgcn_hop, grid, block, 0, stream, X1, cost, neigh, out, n_pairs);
}

// Round 12
// 1639.947 us; speedup vs baseline: 9.7661x; 1.0838x over previous
//
#include <hip/hip_runtime.h>

#define D 128
#define NEIGH 16
#define SINKI 20
#define TINYF 1e-30f

typedef __attribute__((ext_vector_type(8))) _Float16 f16x8;
typedef __attribute__((ext_vector_type(2))) _Float16 f16x2;
typedef __attribute__((ext_vector_type(4))) float f32x4;
typedef __attribute__((ext_vector_type(2))) unsigned int u32x2;

// DPP rotate within 16-lane row: ror by N lanes, accumulate -> full row sum.
template <int N>
__device__ __forceinline__ float rorf(float v) {
  int r = __builtin_amdgcn_update_dpp(0, __builtin_bit_cast(int, v),
                                      0x120 + N, 0xf, 0xf, true);
  return __builtin_bit_cast(float, r);
}

// U row k (256B), byte-swizzle ^((k&15)<<4); read 16B e-slice (ks,g)
__device__ __forceinline__ f16x8 ldfrag(const _Float16* U, int k, int ks, int g) {
  return *(const f16x8*)((const char*)U + k * 256 + (((ks << 6) + (g << 4)) ^ ((k & 15) << 4)));
}

// write U[k][d0..d0+3], d0 = 16rt+4g, same swizzle; RTE casts
__device__ __forceinline__ void stquad(_Float16* U, int k, int rt, int g,
                                       float x, float y, float z, float w) {
  union { _Float16 h[4]; u32x2 u; } P;
  P.h[0] = (_Float16)x; P.h[1] = (_Float16)y;
  P.h[2] = (_Float16)z; P.h[3] = (_Float16)w;
  *(u32x2*)((char*)U + k * 256 + (((rt << 5) + (g << 3)) ^ ((k & 15) << 4))) = P.u;
}

// block = 512 thr = 8 slots (1 wave each); each slot processes a PAIR of nodes.
// U rows: 0..15 = node-A neighbors, 16..31 = node-B neighbors, 32 = self A,
// 33 = self B, 34 = permanent zero row (pad reads), 35 = unused pad.
// LDS = KB(32K) + KA(32K) + 8*9K = 136 KB.
// No TINY in the iteration epilogues: real elements are bounded away from 0
// (x + 1e-30 == x bitwise for x > 1e-23), and pad zeros produce +inf only in
// exec-masked writes (rows 34/35 are init-once, never rewritten).
__global__ __launch_bounds__(512, 1)
void wgcn_hop(const float* __restrict__ Xin,
              const float* __restrict__ Cmat,
              const int* __restrict__ neigh,
              float* __restrict__ Xout,
              int n_pairs) {
  __shared__ _Float16 KB[16384];   // MM1 A-frags: Khat[e=32ks+8g+s][d=16rt+c]
  __shared__ _Float16 KA[16384];   // MM2 A-frags: Khat[d=16rt+c][e=32ks+8g+s]
  __shared__ _Float16 US[8][4608]; // 36 rows x 128 f16 per slot

  const int tid = threadIdx.x;

  for (int idx = tid; idx < 16384; idx += 512) {
    const int s = idx & 7, c = (idx >> 3) & 15, g = (idx >> 7) & 3;
    const int rt = (idx >> 9) & 7, ks = idx >> 12;
    const int e = (ks << 5) + (g << 3) + s;
    const int d = (rt << 4) + c;
    KB[idx] = (_Float16)(16.0f * expf(-10.0f * Cmat[e * 128 + d]));
    KA[idx] = (_Float16)(16.0f * expf(-10.0f * Cmat[d * 128 + e]));
  }
  __syncthreads();

  const int slot = tid >> 6;
  const int lane = tid & 63;
  const int g = lane >> 4;
  const int c = lane & 15;
  const int cc = (c < 2) ? c : 2;          // tile2 read-row offset (row 34 = zeros)
  _Float16* U = US[slot];

  // rows 34/35: permanent zeros, init once
  ((unsigned int*)U)[(34 << 6) | lane] = 0u;
  ((unsigned int*)U)[(35 << 6) | lane] = 0u;

  for (int p = blockIdx.x * 8 + slot; p < n_pairs; p += gridDim.x * 8) {
    const int nA = 2 * p, nB = 2 * p + 1;

    // ---- gather mu for A-neighbors, B-neighbors, selves; normalize ----
    f32x4 mu0[8], mu1[8], muS[8], bvA[8], bvB[8];
    const int srcA = neigh[nA * NEIGH + c];
    const int srcB = neigh[nB * NEIGH + c];
    const int srcS = (c == 1) ? nB : nA;   // c==0 -> A, c==1 -> B, c>=2 dummy
#pragma unroll
    for (int rt = 0; rt < 8; ++rt) {
      mu0[rt] = *(const f32x4*)&Xin[(long)srcA * D + rt * 16 + g * 4];
      mu1[rt] = *(const f32x4*)&Xin[(long)srcB * D + rt * 16 + g * 4];
      muS[rt] = *(const f32x4*)&Xin[(long)srcS * D + rt * 16 + g * 4];
    }
    float s0 = 0.f, s1 = 0.f, sS = 0.f;
#pragma unroll
    for (int rt = 0; rt < 8; ++rt) {
      s0 += mu0[rt].x + mu0[rt].y + mu0[rt].z + mu0[rt].w;
      s1 += mu1[rt].x + mu1[rt].y + mu1[rt].z + mu1[rt].w;
      sS += muS[rt].x + muS[rt].y + muS[rt].z + muS[rt].w;
    }
    s0 += __shfl_xor(s0, 16, 64); s0 += __shfl_xor(s0, 32, 64);
    s1 += __shfl_xor(s1, 16, 64); s1 += __shfl_xor(s1, 32, 64);
    sS += __shfl_xor(sS, 16, 64); sS += __shfl_xor(sS, 32, 64);
    const float i0 = 1024.0f * __builtin_amdgcn_rcpf(s0 + TINYF);
    const float i1 = 1024.0f * __builtin_amdgcn_rcpf(s1 + TINYF);
    const float iS = 1024.0f * __builtin_amdgcn_rcpf(sS + TINYF);
#pragma unroll
    for (int rt = 0; rt < 8; ++rt) {
      mu0[rt].x *= i0; mu0[rt].y *= i0; mu0[rt].z *= i0; mu0[rt].w *= i0;
      mu1[rt].x *= i1; mu1[rt].y *= i1; mu1[rt].z *= i1; mu1[rt].w *= i1;
      muS[rt].x *= iS; muS[rt].y *= iS; muS[rt].z *= iS; muS[rt].w *= iS;
    }

    // ---- u0 = 1 on real rows 0..33 ----
#pragma unroll
    for (int j = 0; j < 34; ++j)
      ((unsigned int*)U)[(j << 6) | lane] = 0x3C003C00u;

    // preload MM1 rt=0 A-frags (loop-invariant K; ready after the fence)
    f16x8 pre1[4], pre2[4];
#pragma unroll
    for (int ks = 0; ks < 4; ++ks)
      pre1[ks] = *(const f16x8*)&KB[(((ks << 3) << 6) + lane) << 3];

    asm volatile("s_waitcnt lgkmcnt(0)" ::: "memory");

#pragma unroll 1
    for (int it = 0; it < SINKI; ++it) {
      // ======== MM1': KTu'[d][k] = sum_e Khat[e][d] * u[k][e] ========
      f16x8 b0[4], b1[4], b2[4];
#pragma unroll
      for (int ks = 0; ks < 4; ++ks) {
        b0[ks] = ldfrag(U, c, ks, g);
        b1[ks] = ldfrag(U, 16 + c, ks, g);
        b2[ks] = ldfrag(U, 32 + cc, ks, g);
      }
#pragma unroll
      for (int rt = 0; rt < 8; ++rt) {
        f32x4 a0 = {0.f, 0.f, 0.f, 0.f}, a1 = a0, a2 = a0;
#pragma unroll
        for (int ks = 0; ks < 4; ++ks) {
          const f16x8 af = (rt == 0) ? pre1[ks]
              : *(const f16x8*)&KB[((((ks << 3) + rt) << 6) + lane) << 3];
          a0 = __builtin_amdgcn_mfma_f32_16x16x32_f16(af, b0[ks], a0, 0, 0, 0);
          a1 = __builtin_amdgcn_mfma_f32_16x16x32_f16(af, b1[ks], a1, 0, 0, 0);
          a2 = __builtin_amdgcn_mfma_f32_16x16x32_f16(af, b2[ks], a2, 0, 0, 0);
        }
        stquad(U, c, rt, g,
               mu0[rt].x * __builtin_amdgcn_rcpf(a0.x),
               mu0[rt].y * __builtin_amdgcn_rcpf(a0.y),
               mu0[rt].z * __builtin_amdgcn_rcpf(a0.z),
               mu0[rt].w * __builtin_amdgcn_rcpf(a0.w));
        stquad(U, 16 + c, rt, g,
               mu1[rt].x * __builtin_amdgcn_rcpf(a1.x),
               mu1[rt].y * __builtin_amdgcn_rcpf(a1.y),
               mu1[rt].z * __builtin_amdgcn_rcpf(a1.z),
               mu1[rt].w * __builtin_amdgcn_rcpf(a1.w));
        if (c < 2)
          stquad(U, 32 + c, rt, g,
                 muS[rt].x * __builtin_amdgcn_rcpf(a2.x),
                 muS[rt].y * __builtin_amdgcn_rcpf(a2.y),
                 muS[rt].z * __builtin_amdgcn_rcpf(a2.z),
                 muS[rt].w * __builtin_amdgcn_rcpf(a2.w));
      }
      // preload MM2 rt=0 A-frags before the fence
#pragma unroll
      for (int ks = 0; ks < 4; ++ks)
        pre2[ks] = *(const f16x8*)&KA[(((ks << 3) << 6) + lane) << 3];
      asm volatile("s_waitcnt lgkmcnt(0)" ::: "memory");

      // ======== MM2': Kv'[d][k] = sum_e Khat[d][e] * v[k][e] ========
#pragma unroll
      for (int ks = 0; ks < 4; ++ks) {
        b0[ks] = ldfrag(U, c, ks, g);
        b1[ks] = ldfrag(U, 16 + c, ks, g);
        b2[ks] = ldfrag(U, 32 + cc, ks, g);
      }
#pragma unroll
      for (int rt = 0; rt < 8; ++rt) {
        f32x4 a0 = {0.f, 0.f, 0.f, 0.f}, a1 = a0, a2 = a0;
#pragma unroll
        for (int ks = 0; ks < 4; ++ks) {
          const f16x8 af = (rt == 0) ? pre2[ks]
              : *(const f16x8*)&KA[((((ks << 3) + rt) << 6) + lane) << 3];
          a0 = __builtin_amdgcn_mfma_f32_16x16x32_f16(af, b0[ks], a0, 0, 0, 0);
          a1 = __builtin_amdgcn_mfma_f32_16x16x32_f16(af, b1[ks], a1, 0, 0, 0);
          a2 = __builtin_amdgcn_mfma_f32_16x16x32_f16(af, b2[ks], a2, 0, 0, 0);
        }
        float bA[4], bB[4];
#pragma unroll
        for (int r = 0; r < 4; ++r) {
          const float tA = ((const float*)&a0)[r];
          const float tB = ((const float*)&a1)[r];
          const float tS = ((const float*)&a2)[r];
          float fA = (c == 0) ? tA * tS : tA;   // fold self-A into lane c==0
          float fB = (c == 1) ? tB * tS : tB;   // fold self-B into lane c==1
          float pA = __builtin_amdgcn_logf(fA);
          float pB = __builtin_amdgcn_logf(fB);
          pA += rorf<1>(pA); pA += rorf<2>(pA); pA += rorf<4>(pA); pA += rorf<8>(pA);
          pB += rorf<1>(pB); pB += rorf<2>(pB); pB += rorf<4>(pB); pB += rorf<8>(pB);
          bA[r] = __builtin_amdgcn_exp2f(pA * (1.0f / 17.0f));
          bB[r] = __builtin_amdgcn_exp2f(pB * (1.0f / 17.0f));
        }
        bvA[rt].x = bA[0]; bvA[rt].y = bA[1]; bvA[rt].z = bA[2]; bvA[rt].w = bA[3];
        bvB[rt].x = bB[0]; bvB[rt].y = bB[1]; bvB[rt].z = bB[2]; bvB[rt].w = bB[3];
        stquad(U, c, rt, g,
               bA[0] * __builtin_amdgcn_rcpf(((const float*)&a0)[0]),
               bA[1] * __builtin_amdgcn_rcpf(((const float*)&a0)[1]),
               bA[2] * __builtin_amdgcn_rcpf(((const float*)&a0)[2]),
               bA[3] * __builtin_amdgcn_rcpf(((const float*)&a0)[3]));
        stquad(U, 16 + c, rt, g,
               bB[0] * __builtin_amdgcn_rcpf(((const float*)&a1)[0]),
               bB[1] * __builtin_amdgcn_rcpf(((const float*)&a1)[1]),
               bB[2] * __builtin_amdgcn_rcpf(((const float*)&a1)[2]),
               bB[3] * __builtin_amdgcn_rcpf(((const float*)&a1)[3]));
        if (c < 2) {
          const float q0 = ((c == 0) ? bA[0] : bB[0]) * __builtin_amdgcn_rcpf(((const float*)&a2)[0]);
          const float q1 = ((c == 0) ? bA[1] : bB[1]) * __builtin_amdgcn_rcpf(((const float*)&a2)[1]);
          const float q2 = ((c == 0) ? bA[2] : bB[2]) * __builtin_amdgcn_rcpf(((const float*)&a2)[2]);
          const float q3 = ((c == 0) ? bA[3] : bB[3]) * __builtin_amdgcn_rcpf(((const float*)&a2)[3]);
          stquad(U, 32 + c, rt, g, q0, q1, q2, q3);
        }
      }
      // preload MM1 rt=0 A-frags for the next iteration before the fence
#pragma unroll
      for (int ks = 0; ks < 4; ++ks)
        pre1[ks] = *(const f16x8*)&KB[(((ks << 3) << 6) + lane) << 3];
      asm volatile("s_waitcnt lgkmcnt(0)" ::: "memory");
    }

    // ---- output: lane c==0 -> node A, c==1 -> node B; b = bhat/1024 (f32 path) ----
    if (c < 2) {
      float* dst = &Xout[(long)((c == 0) ? nA : nB) * D];
#pragma unroll
      for (int rt = 0; rt < 8; ++rt) {
        const f32x4 bq = (c == 0) ? bvA[rt] : bvB[rt];
        f32x4 o;
        o.x = bq.x * (1.0f / 1024.0f);
        o.y = bq.y * (1.0f / 1024.0f);
        o.z = bq.z * (1.0f / 1024.0f);
        o.w = bq.w * (1.0f / 1024.0f);
        *(f32x4*)&dst[rt * 16 + g * 4] = o;
      }
    }
  }
}

extern "C" void kernel_launch(void* const* d_in, const int* in_sizes, int n_in,
                              void* d_out, int out_size, void* d_ws, size_t ws_size,
                              hipStream_t stream) {
  const float* trans_X = (const float*)d_in[0];
  const float* cost = (const float*)d_in[1];
  const int* neigh = (const int*)d_in[2];
  float* out = (float*)d_out;
  float* X1 = (float*)d_ws;   // intermediate hop output, 20000*128 f32
  const int n = in_sizes[0] / D;
  const int n_pairs = n / 2;  // N = 20000 even

  // 250 blocks x 8 slots = 2000 slots -> exactly 5 pairs per slot
  dim3 grid(250), block(512);
  hipLaunchKernelGGL(wgcn_hop, grid, block, 0, stream, trans_X, cost, neigh, X1, n_pairs);
  hipLaunchKernelGGL(wgcn_hop, grid, block, 0, stream, X1, cost, neigh, out, n_pairs);
}